// Round 2
// baseline (1513.372 us; speedup 1.0000x reference)
//
#include <hip/hip_runtime.h>
#include <hip/hip_bf16.h>
#include <stdint.h>

typedef unsigned int uint;
typedef unsigned short ushort;

#define D 128
#define NEG_SLOPE 0.01f
#define BN 128          // nodes per bucket (7 bits localsrc)
#define NCHUNK 256      // partition chunks
#define KMAX 1024       // max buckets supported by LDS arrays (n <= 131072)

using frag_t = __attribute__((ext_vector_type(8))) short;   // 8 bf16 in 4 VGPRs
using f32x4  = __attribute__((ext_vector_type(4))) float;

__device__ __forceinline__ ushort f2bf(float f) {
    __hip_bfloat16 b = __float2bfloat16(f);
    ushort u; __builtin_memcpy(&u, &b, 2); return u;
}
__device__ __forceinline__ float bflo(uint p) { return __uint_as_float(p << 16); }
__device__ __forceinline__ float bfhi(uint p) { return __uint_as_float(p & 0xffff0000u); }

// ---------------------------------------------------------------------------
// K1: h = x @ W^T + b (bf16 out), fused per-node attention scalars:
//     si[n] = h[n]·a_i + b_att,  sj[n] = h[n]·a_j
// Block = 256 thr (4 waves), tile 64 rows x 128 cols.
// MFMA 16x16x32 bf16 C-layout: col=lane&15, row=(lane>>4)*4+reg.
// ---------------------------------------------------------------------------
#define LDK 136   // 128 + 8 bf16 pad

__global__ __launch_bounds__(256) void gemm_h(
    const float* __restrict__ x, const float* __restrict__ W,
    const float* __restrict__ bias, const float* __restrict__ Wa,
    const float* __restrict__ ba,
    ushort* __restrict__ h, float* __restrict__ si, float* __restrict__ sj, int n)
{
    __shared__ ushort xs[64 * LDK];
    __shared__ ushort wsh[128 * LDK];
    const int tid  = threadIdx.x;
    const int row0 = blockIdx.x * 64;

    {
        const int r = tid >> 5;          // 0..7
        const int k = (tid & 31) * 4;    // 0..124
#pragma unroll
        for (int i = 0; i < 8; ++i) {
            int lr = r + 8 * i;
            int gr = row0 + lr;
            int cr = gr < n ? gr : (n - 1);
            float4 v = *(const float4*)(x + (size_t)cr * D + k);
            ushort4 u; u.x = f2bf(v.x); u.y = f2bf(v.y); u.z = f2bf(v.z); u.w = f2bf(v.w);
            *(ushort4*)&xs[lr * LDK + k] = u;
        }
#pragma unroll
        for (int i = 0; i < 16; ++i) {
            int lr = r + 8 * i;
            float4 v = *(const float4*)(W + (size_t)lr * D + k);
            ushort4 u; u.x = f2bf(v.x); u.y = f2bf(v.y); u.z = f2bf(v.z); u.w = f2bf(v.w);
            *(ushort4*)&wsh[lr * LDK + k] = u;
        }
    }
    __syncthreads();

    const int wv   = tid >> 6;
    const int lane = tid & 63;
    const int mr   = lane & 15;
    const int qk   = (lane >> 4) * 8;

    f32x4 acc[8] = {};
    const ushort* xrow = xs + (16 * wv + mr) * LDK;
#pragma unroll
    for (int kk = 0; kk < 4; ++kk) {
        frag_t a = *(const frag_t*)(xrow + kk * 32 + qk);
#pragma unroll
        for (int t = 0; t < 8; ++t) {
            frag_t bf = *(const frag_t*)(wsh + (16 * t + mr) * LDK + kk * 32 + qk);
            acc[t] = __builtin_amdgcn_mfma_f32_16x16x32_bf16(a, bf, acc[t], 0, 0, 0);
        }
    }

    const int crow = 16 * wv + (lane >> 4) * 4;
    float pi[4] = {0.f, 0.f, 0.f, 0.f};
    float pj[4] = {0.f, 0.f, 0.f, 0.f};
#pragma unroll
    for (int t = 0; t < 8; ++t) {
        int col = 16 * t + mr;
        float bb = bias[col];
        float av = Wa[col];
        float bv = Wa[D + col];
#pragma unroll
        for (int r = 0; r < 4; ++r) {
            float v = acc[t][r] + bb;
            int grow = row0 + crow + r;
            if (grow < n) h[(size_t)grow * D + col] = f2bf(v);
            pi[r] += v * av;
            pj[r] += v * bv;
        }
    }
    // reduce over the 16 lanes (mr) of each row group
#pragma unroll
    for (int o = 1; o < 16; o <<= 1) {
#pragma unroll
        for (int r = 0; r < 4; ++r) {
            pi[r] += __shfl_xor(pi[r], o);
            pj[r] += __shfl_xor(pj[r], o);
        }
    }
    if (mr == 0) {
        float bav = ba[0];
#pragma unroll
        for (int r = 0; r < 4; ++r) {
            int grow = row0 + crow + r;
            if (grow < n) { si[grow] = pi[r] + bav; sj[grow] = pj[r]; }
        }
    }
}

// ---------------------------------------------------------------------------
// K2: per-chunk bucket histogram (no global atomics)
// ---------------------------------------------------------------------------
__global__ __launch_bounds__(256) void count_k(
    const int* __restrict__ src, int* __restrict__ counts, int e, int K, int cpb)
{
    __shared__ int hist[KMAX];
    const int c = blockIdx.x;
    for (int b = threadIdx.x; b < K; b += 256) hist[b] = 0;
    __syncthreads();
    const int beg = c * cpb;
    const int end = min(e, beg + cpb);
    for (int i = beg + threadIdx.x; i < end; i += 256)
        atomicAdd(&hist[src[i] >> 7], 1);
    __syncthreads();
    for (int b = threadIdx.x; b < K; b += 256) counts[c * K + b] = hist[b];
}

// K3: per-bucket exclusive scan over chunks -> chunk bases + bucket totals
__global__ __launch_bounds__(256) void scan_chunks(
    const int* __restrict__ counts, int* __restrict__ cbase,
    int* __restrict__ total, int K)
{
    __shared__ int s[NCHUNK];
    const int b = blockIdx.x, t = threadIdx.x;
    int v = counts[t * K + b];
    s[t] = v; __syncthreads();
#pragma unroll
    for (int o = 1; o < NCHUNK; o <<= 1) {
        int tv = (t >= o) ? s[t - o] : 0;
        __syncthreads();
        s[t] += tv;
        __syncthreads();
    }
    cbase[t * K + b] = s[t] - v;
    if (t == NCHUNK - 1) total[b] = s[t];
}

// K4: exclusive scan over bucket totals
__global__ __launch_bounds__(1024) void scan_buckets(
    const int* __restrict__ total, int* __restrict__ bbase, int K)
{
    __shared__ int s[KMAX];
    const int t = threadIdx.x;
    int v = (t < K) ? total[t] : 0;
    s[t] = v; __syncthreads();
#pragma unroll
    for (int o = 1; o < KMAX; o <<= 1) {
        int tv = (t >= o) ? s[t - o] : 0;
        __syncthreads();
        s[t] += tv;
        __syncthreads();
    }
    if (t < K) bbase[t] = s[t] - v;
}

// K5: partition edges into bucket array, block-private LDS cursors.
// Each edge packs to 4B: (localsrc 7b << 17) | dst 17b
__global__ __launch_bounds__(256) void fill_k(
    const int* __restrict__ src, const int* __restrict__ dst,
    const int* __restrict__ cbase, const int* __restrict__ bbase,
    uint* __restrict__ barr, int e, int K, int cpb)
{
    __shared__ int cur[KMAX];
    const int c = blockIdx.x;
    for (int b = threadIdx.x; b < K; b += 256)
        cur[b] = cbase[c * K + b] + bbase[b];
    __syncthreads();
    const int beg = c * cpb;
    const int end = min(e, beg + cpb);
    for (int i = beg + threadIdx.x; i < end; i += 256) {
        int s = src[i], d = dst[i];
        int p = atomicAdd(&cur[s >> 7], 1);
        barr[p] = ((uint)(s & (BN - 1)) << 17) | (uint)d;
    }
}

// ---------------------------------------------------------------------------
// K6: fused aggregation. One block (512 thr, 8 waves) per bucket of 128 nodes.
// LDS fp32 accumulator 128x128 (64 KB) -> 2 blocks/CU.
// ---------------------------------------------------------------------------
__global__ __launch_bounds__(512) void agg_k(
    const ushort* __restrict__ h, const uint* __restrict__ barr,
    const int* __restrict__ bbase, const int* __restrict__ total,
    const float* __restrict__ si, const float* __restrict__ sj,
    float* __restrict__ out, int n)
{
    __shared__ float acc[BN * D];    // 64 KB
    __shared__ float den[BN];
    const int b   = blockIdx.x;
    const int tid = threadIdx.x;
    for (int i = tid; i < BN * D; i += 512) acc[i] = 0.f;
    for (int i = tid; i < BN;     i += 512) den[i] = 0.f;
    __syncthreads();

    const int lane  = tid & 63;
    const int wv    = tid >> 6;
    const int node0 = b << 7;
    const int ebeg  = bbase[b];
    const int ecnt  = total[b];
    int p  = ebeg + (int)(((long long)ecnt * wv) >> 3);
    int we = ebeg + (int)(((long long)ecnt * (wv + 1)) >> 3);

    for (; p + 8 <= we; p += 8) {
        uint wd[8];
#pragma unroll
        for (int j = 0; j < 8; ++j) wd[j] = barr[p + j];
        float wt[8];
#pragma unroll
        for (int j = 0; j < 8; ++j) {
            int dn = wd[j] & 0x1FFFF;
            int ls = wd[j] >> 17;
            float sc = si[node0 + ls] + sj[dn];
            sc = sc >= 0.f ? sc : NEG_SLOPE * sc;
            wt[j] = __expf(sc);
        }
        uint g[8];
#pragma unroll
        for (int j = 0; j < 8; ++j)
            g[j] = *(const uint*)(h + (size_t)(wd[j] & 0x1FFFF) * D + lane * 2);
#pragma unroll
        for (int j = 0; j < 8; ++j) {
            int ls = wd[j] >> 17;
            float* row = &acc[ls * D + lane * 2];
            unsafeAtomicAdd(row,     wt[j] * bflo(g[j]));
            unsafeAtomicAdd(row + 1, wt[j] * bfhi(g[j]));
            if (lane == 0) unsafeAtomicAdd(&den[ls], wt[j]);
        }
    }
    for (; p < we; ++p) {                       // tail
        uint wd = barr[p];
        int dn = wd & 0x1FFFF;
        int ls = wd >> 17;
        float sc = si[node0 + ls] + sj[dn];
        sc = sc >= 0.f ? sc : NEG_SLOPE * sc;
        float wt = __expf(sc);
        uint g = *(const uint*)(h + (size_t)dn * D + lane * 2);
        float* row = &acc[ls * D + lane * 2];
        unsafeAtomicAdd(row,     wt * bflo(g));
        unsafeAtomicAdd(row + 1, wt * bfhi(g));
        if (lane == 0) unsafeAtomicAdd(&den[ls], wt);
    }
    __syncthreads();

    // self-loop + normalize + ELU + store
    for (int idx = wv; idx < BN; idx += 8) {
        int node = node0 + idx;
        if (node >= n) break;
        float sc = si[node] + sj[node];
        sc = sc >= 0.f ? sc : NEG_SLOPE * sc;
        float w_ = __expf(sc);
        uint hv = *(const uint*)(h + (size_t)node * D + lane * 2);
        float dsum = den[idx] + w_;
        float a0 = acc[idx * D + lane * 2]     + w_ * bflo(hv);
        float a1 = acc[idx * D + lane * 2 + 1] + w_ * bfhi(hv);
        float inv = 1.f / dsum;
        a0 *= inv; a1 *= inv;
        a0 = a0 > 0.f ? a0 : expm1f(a0);
        a1 = a1 > 0.f ? a1 : expm1f(a1);
        *(float2*)(out + (size_t)node * D + lane * 2) = make_float2(a0, a1);
    }
}

// ---------------------------------------------------------------------------
extern "C" void kernel_launch(void* const* d_in, const int* in_sizes, int n_in,
                              void* d_out, int out_size, void* d_ws, size_t ws_size,
                              hipStream_t stream)
{
    const float* x  = (const float*)d_in[0];
    const int*   ei = (const int*)  d_in[1];
    const float* Wl = (const float*)d_in[2];
    const float* bl = (const float*)d_in[3];
    const float* Wa = (const float*)d_in[4];
    const float* ba = (const float*)d_in[5];
    const int n = in_sizes[0] / D;
    const int e = in_sizes[1] / 2;
    const int* src = ei;
    const int* dst = ei + e;

    const int K   = (n + BN - 1) / BN;          // 782 buckets
    const int cpb = (e + NCHUNK - 1) / NCHUNK;  // edges per chunk

    char* w = (char*)d_ws;
    size_t off = 0;
    ushort* h      = (ushort*)(w + off); off += (size_t)n * D * 2;      // 25.6 MB
    float*  si     = (float*) (w + off); off += (size_t)n * 4;
    float*  sj     = (float*) (w + off); off += (size_t)n * 4;
    int*    counts = (int*)   (w + off); off += (size_t)NCHUNK * K * 4; // 0.8 MB
    int*    cbase  = (int*)   (w + off); off += (size_t)NCHUNK * K * 4; // 0.8 MB
    int*    total  = (int*)   (w + off); off += (size_t)K * 4;
    int*    bbase  = (int*)   (w + off); off += (size_t)K * 4;
    uint*   barr   = (uint*)  (w + off); off += (size_t)e * 4;          // 6.4 MB

    gemm_h      <<<(n + 63) / 64, 256, 0, stream>>>(x, Wl, bl, Wa, ba, h, si, sj, n);
    count_k     <<<NCHUNK,        256, 0, stream>>>(src, counts, e, K, cpb);
    scan_chunks <<<K,             256, 0, stream>>>(counts, cbase, total, K);
    scan_buckets<<<1,            1024, 0, stream>>>(total, bbase, K);
    fill_k      <<<NCHUNK,        256, 0, stream>>>(src, dst, cbase, bbase, barr, e, K, cpb);
    agg_k       <<<K,             512, 0, stream>>>(h, barr, bbase, total, si, sj, (float*)d_out, n);
}

// Round 3
// 249.666 us; speedup vs baseline: 6.0616x; 6.0616x over previous
//
#include <hip/hip_runtime.h>
#include <hip/hip_bf16.h>
#include <stdint.h>

typedef unsigned int uint;
typedef unsigned short ushort;

#define D 128
#define NEG_SLOPE 0.01f
#define BN 128          // nodes per bucket (7 bits localsrc)
#define NCHUNK 256      // partition chunks
#define KMAX 1024       // max buckets for LDS arrays (n <= 131072)
#define EMAX 4096       // max edges per bucket (mean 2048, std ~45 -> 45 sigma)

using frag_t = __attribute__((ext_vector_type(8))) short;   // 8 bf16 in 4 VGPRs
using f32x4  = __attribute__((ext_vector_type(4))) float;

__device__ __forceinline__ ushort f2bf(float f) {
    __hip_bfloat16 b = __float2bfloat16(f);
    ushort u; __builtin_memcpy(&u, &b, 2); return u;
}
__device__ __forceinline__ float bflo(uint p) { return __uint_as_float(p << 16); }
__device__ __forceinline__ float bfhi(uint p) { return __uint_as_float(p & 0xffff0000u); }

// ---------------------------------------------------------------------------
// K1: h = x @ W^T + b (bf16 out), fused per-node attention scalars:
//     si[n] = h[n]·a_i + b_att,  sj[n] = h[n]·a_j
// ---------------------------------------------------------------------------
#define LDK 136   // 128 + 8 bf16 pad

__global__ __launch_bounds__(256) void gemm_h(
    const float* __restrict__ x, const float* __restrict__ W,
    const float* __restrict__ bias, const float* __restrict__ Wa,
    const float* __restrict__ ba,
    ushort* __restrict__ h, float* __restrict__ si, float* __restrict__ sj, int n)
{
    __shared__ ushort xs[64 * LDK];
    __shared__ ushort wsh[128 * LDK];
    const int tid  = threadIdx.x;
    const int row0 = blockIdx.x * 64;

    {
        const int r = tid >> 5;          // 0..7
        const int k = (tid & 31) * 4;    // 0..124
#pragma unroll
        for (int i = 0; i < 8; ++i) {
            int lr = r + 8 * i;
            int gr = row0 + lr;
            int cr = gr < n ? gr : (n - 1);
            float4 v = *(const float4*)(x + (size_t)cr * D + k);
            ushort4 u; u.x = f2bf(v.x); u.y = f2bf(v.y); u.z = f2bf(v.z); u.w = f2bf(v.w);
            *(ushort4*)&xs[lr * LDK + k] = u;
        }
#pragma unroll
        for (int i = 0; i < 16; ++i) {
            int lr = r + 8 * i;
            float4 v = *(const float4*)(W + (size_t)lr * D + k);
            ushort4 u; u.x = f2bf(v.x); u.y = f2bf(v.y); u.z = f2bf(v.z); u.w = f2bf(v.w);
            *(ushort4*)&wsh[lr * LDK + k] = u;
        }
    }
    __syncthreads();

    const int wv   = tid >> 6;
    const int lane = tid & 63;
    const int mr   = lane & 15;
    const int qk   = (lane >> 4) * 8;

    f32x4 acc[8] = {};
    const ushort* xrow = xs + (16 * wv + mr) * LDK;
#pragma unroll
    for (int kk = 0; kk < 4; ++kk) {
        frag_t a = *(const frag_t*)(xrow + kk * 32 + qk);
#pragma unroll
        for (int t = 0; t < 8; ++t) {
            frag_t bf = *(const frag_t*)(wsh + (16 * t + mr) * LDK + kk * 32 + qk);
            acc[t] = __builtin_amdgcn_mfma_f32_16x16x32_bf16(a, bf, acc[t], 0, 0, 0);
        }
    }

    const int crow = 16 * wv + (lane >> 4) * 4;
    float pi[4] = {0.f, 0.f, 0.f, 0.f};
    float pj[4] = {0.f, 0.f, 0.f, 0.f};
#pragma unroll
    for (int t = 0; t < 8; ++t) {
        int col = 16 * t + mr;
        float bb = bias[col];
        float av = Wa[col];
        float bv = Wa[D + col];
#pragma unroll
        for (int r = 0; r < 4; ++r) {
            float v = acc[t][r] + bb;
            int grow = row0 + crow + r;
            if (grow < n) h[(size_t)grow * D + col] = f2bf(v);
            pi[r] += v * av;
            pj[r] += v * bv;
        }
    }
#pragma unroll
    for (int o = 1; o < 16; o <<= 1) {
#pragma unroll
        for (int r = 0; r < 4; ++r) {
            pi[r] += __shfl_xor(pi[r], o);
            pj[r] += __shfl_xor(pj[r], o);
        }
    }
    if (mr == 0) {
        float bav = ba[0];
#pragma unroll
        for (int r = 0; r < 4; ++r) {
            int grow = row0 + crow + r;
            if (grow < n) { si[grow] = pi[r] + bav; sj[grow] = pj[r]; }
        }
    }
}

// ---------------------------------------------------------------------------
// K2: per-chunk bucket histogram (no global atomics)
// ---------------------------------------------------------------------------
__global__ __launch_bounds__(256) void count_k(
    const int* __restrict__ src, int* __restrict__ counts, int e, int K, int cpb)
{
    __shared__ int hist[KMAX];
    const int c = blockIdx.x;
    for (int b = threadIdx.x; b < K; b += 256) hist[b] = 0;
    __syncthreads();
    const int beg = c * cpb;
    const int end = min(e, beg + cpb);
    for (int i = beg + threadIdx.x; i < end; i += 256)
        atomicAdd(&hist[src[i] >> 7], 1);
    __syncthreads();
    for (int b = threadIdx.x; b < K; b += 256) counts[c * K + b] = hist[b];
}

// K3: per-bucket exclusive scan over chunks -> chunk bases + bucket totals
__global__ __launch_bounds__(256) void scan_chunks(
    const int* __restrict__ counts, int* __restrict__ cbase,
    int* __restrict__ total, int K)
{
    __shared__ int s[NCHUNK];
    const int b = blockIdx.x, t = threadIdx.x;
    int v = counts[t * K + b];
    s[t] = v; __syncthreads();
#pragma unroll
    for (int o = 1; o < NCHUNK; o <<= 1) {
        int tv = (t >= o) ? s[t - o] : 0;
        __syncthreads();
        s[t] += tv;
        __syncthreads();
    }
    cbase[t * K + b] = s[t] - v;
    if (t == NCHUNK - 1) total[b] = s[t];
}

// K4: exclusive scan over bucket totals
__global__ __launch_bounds__(1024) void scan_buckets(
    const int* __restrict__ total, int* __restrict__ bbase, int K)
{
    __shared__ int s[KMAX];
    const int t = threadIdx.x;
    int v = (t < K) ? total[t] : 0;
    s[t] = v; __syncthreads();
#pragma unroll
    for (int o = 1; o < KMAX; o <<= 1) {
        int tv = (t >= o) ? s[t - o] : 0;
        __syncthreads();
        s[t] += tv;
        __syncthreads();
    }
    if (t < K) bbase[t] = s[t] - v;
}

// K5: partition edges into bucket array, block-private LDS cursors.
// Pack 4B/edge: (localsrc 7b << 17) | dst 17b
__global__ __launch_bounds__(256) void fill_k(
    const int* __restrict__ src, const int* __restrict__ dst,
    const int* __restrict__ cbase, const int* __restrict__ bbase,
    uint* __restrict__ barr, int e, int K, int cpb)
{
    __shared__ int cur[KMAX];
    const int c = blockIdx.x;
    for (int b = threadIdx.x; b < K; b += 256)
        cur[b] = cbase[c * K + b] + bbase[b];
    __syncthreads();
    const int beg = c * cpb;
    const int end = min(e, beg + cpb);
    for (int i = beg + threadIdx.x; i < end; i += 256) {
        int s = src[i], d = dst[i];
        int p = atomicAdd(&cur[s >> 7], 1);
        barr[p] = ((uint)(s & (BN - 1)) << 17) | (uint)d;
    }
}

// ---------------------------------------------------------------------------
// K6: per-bucket agg. Block = 512 thr (8 waves). In-LDS counting sort by
// localsrc -> exact per-node segments -> register accumulation, NO fp atomics.
// ---------------------------------------------------------------------------
__global__ __launch_bounds__(512) void agg_k(
    const ushort* __restrict__ h, const uint* __restrict__ barr,
    const int* __restrict__ bbase, const int* __restrict__ total,
    const float* __restrict__ si, const float* __restrict__ sj,
    float* __restrict__ out, int n)
{
    __shared__ uint se[EMAX];        // sorted edges (16 KB)
    __shared__ int hist[BN];
    __shared__ int base[BN];
    __shared__ int cur[BN];
    const int b   = blockIdx.x;
    const int tid = threadIdx.x;
    const int lane = tid & 63;
    const int wv   = tid >> 6;
    const int node0 = b << 7;

    for (int i = tid; i < BN; i += 512) hist[i] = 0;
    __syncthreads();

    const int ecnt = total[b];
    const uint* eb = barr + bbase[b];

    // pass 1: histogram over localsrc (int LDS atomics, 128 counters)
    for (int i = tid; i < ecnt; i += 512)
        atomicAdd(&hist[eb[i] >> 17], 1);
    __syncthreads();

    // exclusive scan of 128 counters by wave 0 (2 per lane)
    if (tid < 64) {
        int v0 = hist[2 * tid], v1 = hist[2 * tid + 1];
        int s = v0 + v1;
#pragma unroll
        for (int o = 1; o < 64; o <<= 1) {
            int t = __shfl_up(s, o);
            if (tid >= o) s += t;
        }
        int excl = s - (v0 + v1);
        base[2 * tid] = excl;      cur[2 * tid] = excl;
        base[2 * tid + 1] = excl + v0; cur[2 * tid + 1] = excl + v0;
    }
    __syncthreads();

    // pass 2: scatter into sorted LDS array (int cursor atomics)
    for (int i = tid; i < ecnt; i += 512) {
        uint w = eb[i];
        int p = atomicAdd(&cur[w >> 17], 1);
        se[p] = w;
    }
    __syncthreads();

    // aggregation: wave wv owns nodes [wv*16, wv*16+16)
    for (int t = 0; t < 16; ++t) {
        int ls = wv * 16 + t;
        int node = node0 + ls;
        if (node >= n) break;

        float s_i = si[node];
        // self-loop
        float sc = s_i + sj[node];
        sc = sc >= 0.f ? sc : NEG_SLOPE * sc;
        float w_ = __expf(sc);
        uint hv = *(const uint*)(h + (size_t)node * D + lane * 2);
        float a0 = w_ * bflo(hv), a1 = w_ * bfhi(hv);
        float denom = w_;

        const int c = hist[ls];
        const uint* seg = se + base[ls];
        int j = 0;
        for (; j + 4 <= c; j += 4) {
            uint w0 = seg[j], w1 = seg[j + 1], w2 = seg[j + 2], w3 = seg[j + 3];
            int d0 = w0 & 0x1FFFF, d1 = w1 & 0x1FFFF;
            int d2 = w2 & 0x1FFFF, d3 = w3 & 0x1FFFF;
            uint g0 = *(const uint*)(h + (size_t)d0 * D + lane * 2);
            uint g1 = *(const uint*)(h + (size_t)d1 * D + lane * 2);
            uint g2 = *(const uint*)(h + (size_t)d2 * D + lane * 2);
            uint g3 = *(const uint*)(h + (size_t)d3 * D + lane * 2);
            float t0 = s_i + sj[d0], t1 = s_i + sj[d1];
            float t2 = s_i + sj[d2], t3 = s_i + sj[d3];
            t0 = t0 >= 0.f ? t0 : NEG_SLOPE * t0;
            t1 = t1 >= 0.f ? t1 : NEG_SLOPE * t1;
            t2 = t2 >= 0.f ? t2 : NEG_SLOPE * t2;
            t3 = t3 >= 0.f ? t3 : NEG_SLOPE * t3;
            float e0 = __expf(t0), e1 = __expf(t1);
            float e2 = __expf(t2), e3 = __expf(t3);
            denom += (e0 + e1) + (e2 + e3);
            a0 += e0 * bflo(g0) + e1 * bflo(g1) + e2 * bflo(g2) + e3 * bflo(g3);
            a1 += e0 * bfhi(g0) + e1 * bfhi(g1) + e2 * bfhi(g2) + e3 * bfhi(g3);
        }
        for (; j < c; ++j) {
            uint w = seg[j];
            int dn = w & 0x1FFFF;
            uint g = *(const uint*)(h + (size_t)dn * D + lane * 2);
            float ts = s_i + sj[dn];
            ts = ts >= 0.f ? ts : NEG_SLOPE * ts;
            float we = __expf(ts);
            denom += we;
            a0 += we * bflo(g);
            a1 += we * bfhi(g);
        }

        float inv = 1.f / denom;
        a0 *= inv; a1 *= inv;
        a0 = a0 > 0.f ? a0 : expm1f(a0);
        a1 = a1 > 0.f ? a1 : expm1f(a1);
        *(float2*)(out + (size_t)node * D + lane * 2) = make_float2(a0, a1);
    }
}

// ---------------------------------------------------------------------------
extern "C" void kernel_launch(void* const* d_in, const int* in_sizes, int n_in,
                              void* d_out, int out_size, void* d_ws, size_t ws_size,
                              hipStream_t stream)
{
    const float* x  = (const float*)d_in[0];
    const int*   ei = (const int*)  d_in[1];
    const float* Wl = (const float*)d_in[2];
    const float* bl = (const float*)d_in[3];
    const float* Wa = (const float*)d_in[4];
    const float* ba = (const float*)d_in[5];
    const int n = in_sizes[0] / D;
    const int e = in_sizes[1] / 2;
    const int* src = ei;
    const int* dst = ei + e;

    const int K   = (n + BN - 1) / BN;          // 782 buckets
    const int cpb = (e + NCHUNK - 1) / NCHUNK;  // edges per chunk

    char* w = (char*)d_ws;
    size_t off = 0;
    ushort* h      = (ushort*)(w + off); off += (size_t)n * D * 2;      // 25.6 MB
    float*  si     = (float*) (w + off); off += (size_t)n * 4;
    float*  sj     = (float*) (w + off); off += (size_t)n * 4;
    int*    counts = (int*)   (w + off); off += (size_t)NCHUNK * K * 4;
    int*    cbase  = (int*)   (w + off); off += (size_t)NCHUNK * K * 4;
    int*    total  = (int*)   (w + off); off += (size_t)K * 4;
    int*    bbase  = (int*)   (w + off); off += (size_t)K * 4;
    uint*   barr   = (uint*)  (w + off); off += (size_t)e * 4;          // 6.4 MB

    gemm_h      <<<(n + 63) / 64, 256, 0, stream>>>(x, Wl, bl, Wa, ba, h, si, sj, n);
    count_k     <<<NCHUNK,        256, 0, stream>>>(src, counts, e, K, cpb);
    scan_chunks <<<K,             256, 0, stream>>>(counts, cbase, total, K);
    scan_buckets<<<1,            1024, 0, stream>>>(total, bbase, K);
    fill_k      <<<NCHUNK,        256, 0, stream>>>(src, dst, cbase, bbase, barr, e, K, cpb);
    agg_k       <<<K,             512, 0, stream>>>(h, barr, bbase, total, si, sj, (float*)d_out, n);
}